// Round 2
// baseline (332.286 us; speedup 1.0000x reference)
//
#include <hip/hip_runtime.h>

typedef unsigned short u16;
typedef unsigned int   u32;
typedef __attribute__((ext_vector_type(8))) __bf16 bf16x8;
typedef __attribute__((ext_vector_type(4))) float  f32x4;

#define D_DIM 2048
#define N_TOK 8192

// f32 -> bf16 round-to-nearest-even (values are finite, no NaN handling needed)
__device__ __forceinline__ u16 f2bf(float f) {
  u32 u = __float_as_uint(f);
  u32 r = (u + 0x7fffu + ((u >> 16) & 1u)) >> 16;
  return (u16)r;
}

__device__ __forceinline__ void gl16(const void* g, void* l) {
  __builtin_amdgcn_global_load_lds((const __attribute__((address_space(1))) void*)g,
                                   (__attribute__((address_space(3))) void*)l,
                                   16, 0, 0);
}

// ---------- elementwise f32 -> bf16 (vectorized, grid-stride) ----------
__global__ __launch_bounds__(256) void cvt_f32_bf16(const float* __restrict__ in,
                                                    u16* __restrict__ out, int n4) {
  int idx = blockIdx.x * 256 + threadIdx.x;
  int stride = gridDim.x * 256;
  for (int i = idx; i < n4; i += stride) {
    float4 v = ((const float4*)in)[i];
    ushort4 o;
    o.x = f2bf(v.x); o.y = f2bf(v.y); o.z = f2bf(v.z); o.w = f2bf(v.w);
    ((ushort4*)out)[i] = o;
  }
}

// ---------- row-wise L2 normalize of direction [D][D] -> bf16 ----------
__global__ __launch_bounds__(256) void normalize_rows(const float* __restrict__ dir,
                                                      u16* __restrict__ out) {
  const int row = blockIdx.x;
  const int tid = threadIdx.x;
  const float4* r = (const float4*)(dir + (size_t)row * D_DIM);
  float4 v0 = r[tid * 2 + 0];
  float4 v1 = r[tid * 2 + 1];
  float ss = v0.x*v0.x + v0.y*v0.y + v0.z*v0.z + v0.w*v0.w
           + v1.x*v1.x + v1.y*v1.y + v1.z*v1.z + v1.w*v1.w;
  #pragma unroll
  for (int off = 32; off > 0; off >>= 1) ss += __shfl_down(ss, off);
  __shared__ float red[4];
  __shared__ float invs;
  if ((tid & 63) == 0) red[tid >> 6] = ss;
  __syncthreads();
  if (tid == 0) {
    float t = red[0] + red[1] + red[2] + red[3];
    invs = 1.0f / fmaxf(sqrtf(t), 1e-12f);
  }
  __syncthreads();
  float inv = invs;
  ushort4 o0, o1;
  o0.x = f2bf(v0.x * inv); o0.y = f2bf(v0.y * inv);
  o0.z = f2bf(v0.z * inv); o0.w = f2bf(v0.w * inv);
  o1.x = f2bf(v1.x * inv); o1.y = f2bf(v1.y * inv);
  o1.z = f2bf(v1.z * inv); o1.w = f2bf(v1.w * inv);
  ushort4* ow = (ushort4*)(out + (size_t)row * D_DIM);
  ow[tid * 2 + 0] = o0;
  ow[tid * 2 + 1] = o1;
}

// ---------- scale = ||magnitude||_2 * (alpha/D) ----------
__global__ __launch_bounds__(256) void mag_scale_k(const float* __restrict__ m,
                                                   float* __restrict__ scale,
                                                   int n, float scaling) {
  const int tid = threadIdx.x;
  float ss = 0.0f;
  for (int i = tid; i < n / 4; i += 256) {
    float4 v = ((const float4*)m)[i];
    ss += v.x*v.x + v.y*v.y + v.z*v.z + v.w*v.w;
  }
  #pragma unroll
  for (int off = 32; off > 0; off >>= 1) ss += __shfl_down(ss, off);
  __shared__ float red[4];
  if ((tid & 63) == 0) red[tid >> 6] = ss;
  __syncthreads();
  if (tid == 0) {
    float t = red[0] + red[1] + red[2] + red[3];
    scale[0] = sqrtf(t) * scaling;
  }
}

// ---------- NT bf16 GEMM: out[m,n] = scale * sum_k A[m,k]*B[n,k] ----------
// A: [M][K] bf16 row-major, B: [N][K] bf16 row-major. 128x128 tile, BK=64,
// 4 waves (2x2), 16x16x32 MFMA, 4x4 frags/wave. global_load_lds(16B) staging
// with pre-swizzled source; XOR slot swizzle (slot ^= row&7) on ds_read_b128.
template <int OUT_BF16>
__global__ __launch_bounds__(256)
void gemm_nt(const u16* __restrict__ A, const u16* __restrict__ B,
             void* __restrict__ Cv, int M, int Nn, int K,
             const float* __restrict__ scale_ptr) {
  __shared__ __align__(16) u16 lA[128 * 64];
  __shared__ __align__(16) u16 lB[128 * 64];
  const int tid  = threadIdx.x;
  const int lane = tid & 63;
  const int wave = tid >> 6;
  const int wr = wave >> 1, wc = wave & 1;
  const int row0 = blockIdx.y * 128, col0 = blockIdx.x * 128;

  const u16* Ag = A + (size_t)row0 * K;
  const u16* Bg = B + (size_t)col0 * K;

  f32x4 acc[4][4];
  #pragma unroll
  for (int i = 0; i < 4; ++i)
    #pragma unroll
    for (int j = 0; j < 4; ++j)
      acc[i][j] = (f32x4){0.0f, 0.0f, 0.0f, 0.0f};

  const int rsub = lane >> 3;  // row within 8-row chunk
  const int sm   = lane & 7;   // memory slot (16B units within 128B row)

  for (int k0 = 0; k0 < K; k0 += 64) {
    // stage A,B tiles: 16 chunks x 1024B each; wave w handles chunks w*4..w*4+3
    #pragma unroll
    for (int j = 0; j < 4; ++j) {
      int c  = wave * 4 + j;
      int rt = c * 8 + rsub;               // tile row 0..127
      int ssrc = sm ^ (rt & 7);            // pre-swizzled source slot
      gl16(Ag + (size_t)rt * K + k0 + ssrc * 8, &lA[c * 512 + lane * 8]);
      gl16(Bg + (size_t)rt * K + k0 + ssrc * 8, &lB[c * 512 + lane * 8]);
    }
    __syncthreads();   // drains vmcnt (compiler emits vmcnt(0) before barrier)

    #pragma unroll
    for (int ks = 0; ks < 2; ++ks) {
      bf16x8 af[4], bfr[4];
      #pragma unroll
      for (int mi = 0; mi < 4; ++mi) {
        int ra = wr * 64 + mi * 16 + (lane & 15);
        int sa = (ks * 4 + (lane >> 4)) ^ (ra & 7);
        af[mi] = *(const bf16x8*)&lA[ra * 64 + sa * 8];
        int rb = wc * 64 + mi * 16 + (lane & 15);
        int sb = (ks * 4 + (lane >> 4)) ^ (rb & 7);
        bfr[mi] = *(const bf16x8*)&lB[rb * 64 + sb * 8];
      }
      #pragma unroll
      for (int mi = 0; mi < 4; ++mi)
        #pragma unroll
        for (int ni = 0; ni < 4; ++ni)
          acc[mi][ni] = __builtin_amdgcn_mfma_f32_16x16x32_bf16(
              af[mi], bfr[ni], acc[mi][ni], 0, 0, 0);
    }
    __syncthreads();
  }

  float scl = scale_ptr ? scale_ptr[0] : 1.0f;
  // C/D layout (verified m89/m91): col = lane&15, row = (lane>>4)*4 + reg
  const int orow = row0 + wr * 64 + (lane >> 4) * 4;
  const int ocol = col0 + wc * 64 + (lane & 15);
  #pragma unroll
  for (int mi = 0; mi < 4; ++mi) {
    #pragma unroll
    for (int ni = 0; ni < 4; ++ni) {
      #pragma unroll
      for (int r = 0; r < 4; ++r) {
        int gr = orow + mi * 16 + r;
        int gc = ocol + ni * 16;
        float v = acc[mi][ni][r] * scl;
        if (OUT_BF16) ((u16*)Cv)[(size_t)gr * Nn + gc] = f2bf(v);
        else          ((float*)Cv)[(size_t)gr * Nn + gc] = v;
      }
    }
  }
}

extern "C" void kernel_launch(void* const* d_in, const int* in_sizes, int n_in,
                              void* d_out, int out_size, void* d_ws, size_t ws_size,
                              hipStream_t stream) {
  const float* x    = (const float*)d_in[0];  // [N,D]
  const float* lorA = (const float*)d_in[1];  // [D,D] (rank, in)
  const float* lorB = (const float*)d_in[2];  // [D,D] (out, rank)
  const float* mag  = (const float*)d_in[3];  // [D]
  const float* dir  = (const float*)d_in[4];  // [D,D] (out, rank)
  float* out = (float*)d_out;

  char* ws = (char*)d_ws;
  // workspace layout (bytes)
  u16*   xb  = (u16*)(ws);                        // 33,554,432: x in bf16
  u16*   Ab  = (u16*)(ws + 33554432);             //  8,388,608: lora_A bf16
  u16*   Bb  = (u16*)(ws + 41943040);             //  8,388,608: lora_B bf16
  u16*   Db  = (u16*)(ws + 50331648);             //  8,388,608: dirn bf16 (reused for WfT)
  u16*   CT  = (u16*)(ws + 58720256);             //  8,388,608: C^T bf16
  float* scl = (float*)(ws + 67108864);           //  4: mag*scaling
  u16*   WfT = Db;  // dirn dead after GEMM1; alias

  // prep
  cvt_f32_bf16<<<2048, 256, 0, stream>>>(x,    xb, N_TOK * D_DIM / 4);
  cvt_f32_bf16<<<1024, 256, 0, stream>>>(lorA, Ab, D_DIM * D_DIM / 4);
  cvt_f32_bf16<<<1024, 256, 0, stream>>>(lorB, Bb, D_DIM * D_DIM / 4);
  normalize_rows<<<D_DIM, 256, 0, stream>>>(dir, Db);
  mag_scale_k<<<1, 256, 0, stream>>>(mag, scl, D_DIM, 16.0f / 2048.0f);

  // GEMM1: CT[o,r] = sum_i dirn[o,i] * A[r,i]       (= (A @ dirn^T)^T)
  gemm_nt<1><<<dim3(D_DIM / 128, D_DIM / 128), 256, 0, stream>>>(
      Db, Ab, CT, D_DIM, D_DIM, D_DIM, nullptr);
  // GEMM2: WfT[o,p] = sum_r CT[o,r] * B[p,r]        (= (B @ C)^T)
  gemm_nt<1><<<dim3(D_DIM / 128, D_DIM / 128), 256, 0, stream>>>(
      CT, Bb, WfT, D_DIM, D_DIM, D_DIM, nullptr);
  // GEMM3: out[n,o] = scale * sum_p x[n,p] * WfT[o,p]
  gemm_nt<0><<<dim3(D_DIM / 128, N_TOK / 128), 256, 0, stream>>>(
      xb, WfT, out, N_TOK, D_DIM, D_DIM, scl);
}

// Round 4
// 312.939 us; speedup vs baseline: 1.0618x; 1.0618x over previous
//
#include <hip/hip_runtime.h>

typedef unsigned short u16;
typedef unsigned int   u32;
typedef __attribute__((ext_vector_type(8))) __bf16 bf16x8;
typedef __attribute__((ext_vector_type(4))) float  f32x4;

#define D_DIM 2048
#define N_TOK 8192

// f32 -> bf16 round-to-nearest-even
__device__ __forceinline__ u16 f2bf(float f) {
  u32 u = __float_as_uint(f);
  u32 r = (u + 0x7fffu + ((u >> 16) & 1u)) >> 16;
  return (u16)r;
}

__device__ __forceinline__ void gl16(const void* g, void* l) {
  __builtin_amdgcn_global_load_lds((const __attribute__((address_space(1))) void*)g,
                                   (__attribute__((address_space(3))) void*)l,
                                   16, 0, 0);
}

// ---------- elementwise f32 -> bf16 ----------
__global__ __launch_bounds__(256) void cvt_f32_bf16(const float* __restrict__ in,
                                                    u16* __restrict__ out, int n4) {
  int idx = blockIdx.x * 256 + threadIdx.x;
  int stride = gridDim.x * 256;
  for (int i = idx; i < n4; i += stride) {
    float4 v = ((const float4*)in)[i];
    ushort4 o;
    o.x = f2bf(v.x); o.y = f2bf(v.y); o.z = f2bf(v.z); o.w = f2bf(v.w);
    ((ushort4*)out)[i] = o;
  }
}

// ---------- row-wise L2 normalize of direction [D][D] -> bf16 ----------
__global__ __launch_bounds__(256) void normalize_rows(const float* __restrict__ dir,
                                                      u16* __restrict__ out) {
  const int row = blockIdx.x;
  const int tid = threadIdx.x;
  const float4* r = (const float4*)(dir + (size_t)row * D_DIM);
  float4 v0 = r[tid * 2 + 0];
  float4 v1 = r[tid * 2 + 1];
  float ss = v0.x*v0.x + v0.y*v0.y + v0.z*v0.z + v0.w*v0.w
           + v1.x*v1.x + v1.y*v1.y + v1.z*v1.z + v1.w*v1.w;
  #pragma unroll
  for (int off = 32; off > 0; off >>= 1) ss += __shfl_down(ss, off);
  __shared__ float red[4];
  __shared__ float invs;
  if ((tid & 63) == 0) red[tid >> 6] = ss;
  __syncthreads();
  if (tid == 0) {
    float t = red[0] + red[1] + red[2] + red[3];
    invs = 1.0f / fmaxf(sqrtf(t), 1e-12f);
  }
  __syncthreads();
  float inv = invs;
  ushort4 o0, o1;
  o0.x = f2bf(v0.x * inv); o0.y = f2bf(v0.y * inv);
  o0.z = f2bf(v0.z * inv); o0.w = f2bf(v0.w * inv);
  o1.x = f2bf(v1.x * inv); o1.y = f2bf(v1.y * inv);
  o1.z = f2bf(v1.z * inv); o1.w = f2bf(v1.w * inv);
  ushort4* ow = (ushort4*)(out + (size_t)row * D_DIM);
  ow[tid * 2 + 0] = o0;
  ow[tid * 2 + 1] = o1;
}

// ---------- scale = ||magnitude||_2 * (alpha/D) ----------
__global__ __launch_bounds__(256) void mag_scale_k(const float* __restrict__ m,
                                                   float* __restrict__ scale,
                                                   int n, float scaling) {
  const int tid = threadIdx.x;
  float ss = 0.0f;
  for (int i = tid; i < n / 4; i += 256) {
    float4 v = ((const float4*)m)[i];
    ss += v.x*v.x + v.y*v.y + v.z*v.z + v.w*v.w;
  }
  #pragma unroll
  for (int off = 32; off > 0; off >>= 1) ss += __shfl_down(ss, off);
  __shared__ float red[4];
  if ((tid & 63) == 0) red[tid >> 6] = ss;
  __syncthreads();
  if (tid == 0) {
    float t = red[0] + red[1] + red[2] + red[3];
    scale[0] = sqrtf(t) * scaling;
  }
}

// ---------- NT bf16 GEMM, 128x128 tile (for 2048-shaped GEMMs) ----------
template <int OUT_BF16>
__global__ __launch_bounds__(256)
void gemm_nt(const u16* __restrict__ A, const u16* __restrict__ B,
             void* __restrict__ Cv, int M, int Nn, int K,
             const float* __restrict__ scale_ptr) {
  __shared__ __align__(16) u16 lA[128 * 64];
  __shared__ __align__(16) u16 lB[128 * 64];
  const int tid  = threadIdx.x;
  const int lane = tid & 63;
  const int wave = tid >> 6;
  const int wr = wave >> 1, wc = wave & 1;
  const int row0 = blockIdx.y * 128, col0 = blockIdx.x * 128;

  const u16* Ag = A + (size_t)row0 * K;
  const u16* Bg = B + (size_t)col0 * K;

  f32x4 acc[4][4];
  #pragma unroll
  for (int i = 0; i < 4; ++i)
    #pragma unroll
    for (int j = 0; j < 4; ++j)
      acc[i][j] = (f32x4){0.0f, 0.0f, 0.0f, 0.0f};

  const int rsub = lane >> 3;
  const int sm   = lane & 7;

  for (int k0 = 0; k0 < K; k0 += 64) {
    #pragma unroll
    for (int j = 0; j < 4; ++j) {
      int c  = wave * 4 + j;
      int rt = c * 8 + rsub;
      int ssrc = sm ^ (rt & 7);
      gl16(Ag + (size_t)rt * K + k0 + ssrc * 8, &lA[c * 512 + lane * 8]);
      gl16(Bg + (size_t)rt * K + k0 + ssrc * 8, &lB[c * 512 + lane * 8]);
    }
    __syncthreads();

    #pragma unroll
    for (int ks = 0; ks < 2; ++ks) {
      bf16x8 af[4], bfr[4];
      #pragma unroll
      for (int mi = 0; mi < 4; ++mi) {
        int ra = wr * 64 + mi * 16 + (lane & 15);
        int sa = (ks * 4 + (lane >> 4)) ^ (ra & 7);
        af[mi] = *(const bf16x8*)&lA[ra * 64 + sa * 8];
        int rb = wc * 64 + mi * 16 + (lane & 15);
        int sb = (ks * 4 + (lane >> 4)) ^ (rb & 7);
        bfr[mi] = *(const bf16x8*)&lB[rb * 64 + sb * 8];
      }
      #pragma unroll
      for (int mi = 0; mi < 4; ++mi)
        #pragma unroll
        for (int ni = 0; ni < 4; ++ni)
          acc[mi][ni] = __builtin_amdgcn_mfma_f32_16x16x32_bf16(
              af[mi], bfr[ni], acc[mi][ni], 0, 0, 0);
    }
    __syncthreads();
  }

  float scl = scale_ptr ? scale_ptr[0] : 1.0f;
  const int orow = row0 + wr * 64 + (lane >> 4) * 4;
  const int ocol = col0 + wc * 64 + (lane & 15);
  #pragma unroll
  for (int mi = 0; mi < 4; ++mi) {
    #pragma unroll
    for (int ni = 0; ni < 4; ++ni) {
      #pragma unroll
      for (int r = 0; r < 4; ++r) {
        int gr = orow + mi * 16 + r;
        int gc = ocol + ni * 16;
        float v = acc[mi][ni][r] * scl;
        if (OUT_BF16) ((u16*)Cv)[(size_t)gr * Nn + gc] = f2bf(v);
        else          ((float*)Cv)[(size_t)gr * Nn + gc] = v;
      }
    }
  }
}

// ---------- NT bf16 GEMM, 256x256 tile, 8-phase counted-vmcnt schedule ----------
// 8 waves (2Mx4N), 512 thr. LDS: 2 dbuf x [Alo,Ahi,Blo,Bhi] x 128x64 bf16 = 128 KiB.
// READ LIVENESS (the R3 bug): A halves are read by SOME wave at BOTH p0 (rows
// 0..63 of each wave's half) and p2 (rows 64..127); B halves at BOTH p0 and p1.
// => A halves die at p2-end barrier; B halves die at p1-end barrier.
// STAGING (into buffer b = t&1, for tile t+2, same parity):
//   p2 stages Blo(t+2), Bhi(t+2)   (B dead since p1-end)
//   p3 stages Alo(t+2), Ahi(t+2)   (A dead since p2-end)
// Per wave: 8 staging instrs/tile. Boundary: vmcnt(8) keeps exactly this
// tile's 8 in flight, drains older -> tile t+1 fully landed. vmcnt(0) for the
// last two boundaries. Prologue: stage tiles 0+1 (16 instrs), vmcnt(8).
#define STG(tile, half) do {                                                   \
    const u16* G_ = ((half) < 2) ? (A + (size_t)(row0 + ((half)&1)*128) * K)   \
                                 : (B + (size_t)(col0 + ((half)&1)*128) * K);  \
    u16* L_ = &lds[(tile)&1][half][0];                                         \
    const int k0_ = (tile) << 6;                                               \
    { int idx = tid;       int rt = idx >> 3, sm2 = idx & 7;                   \
      gl16(G_ + (size_t)rt*K + k0_ + (sm2 ^ (rt&7))*8, L_ + idx*8); }          \
    { int idx = 512 + tid; int rt = idx >> 3, sm2 = idx & 7;                   \
      gl16(G_ + (size_t)rt*K + k0_ + (sm2 ^ (rt&7))*8, L_ + idx*8); }          \
  } while (0)

#define RDA(b, mi, ks) (*(const bf16x8*)&lds[b][wr][((mi)*16 + fr)*64 + ((((ks)*4 + fs) ^ (fr & 7)))*8])
#define RDB(b, ni, ks) (*(const bf16x8*)&lds[b][2 + ((wc*64 + (ni)*16 + fr) >> 7)][((wc*64 + (ni)*16 + fr) & 127)*64 + ((((ks)*4 + fs) ^ (fr & 7)))*8])
#define MFMA(a, bb, c) __builtin_amdgcn_mfma_f32_16x16x32_bf16(a, bb, c, 0, 0, 0)

template <int OUT_BF16>
__global__ __launch_bounds__(512, 2)
void gemm_nt8(const u16* __restrict__ A, const u16* __restrict__ B,
              void* __restrict__ Cv, int M, int Nn, int K,
              const float* __restrict__ scale_ptr) {
  __shared__ __align__(16) u16 lds[2][4][128 * 64];  // 128 KiB
  const int tid  = threadIdx.x;
  const int lane = tid & 63;
  const int wave = tid >> 6;
  const int wr = wave >> 2;      // 0..1  (M half of waves)
  const int wc = wave & 3;       // 0..3  (N quarter of waves)
  const int row0 = blockIdx.y * 256, col0 = blockIdx.x * 256;
  const int NT = K >> 6;
  const int fr = lane & 15, fs = lane >> 4;

  f32x4 acc[8][4];
  #pragma unroll
  for (int i = 0; i < 8; ++i)
    #pragma unroll
    for (int j = 0; j < 4; ++j)
      acc[i][j] = (f32x4){0.0f, 0.0f, 0.0f, 0.0f};

  // prologue: stage tiles 0 and 1 fully; land tile 0, keep tile 1 in flight
  STG(0, 0); STG(0, 1); STG(0, 2); STG(0, 3);
  if (NT > 1) {
    STG(1, 0); STG(1, 1); STG(1, 2); STG(1, 3);
    asm volatile("s_waitcnt vmcnt(8)" ::: "memory");
  } else {
    asm volatile("s_waitcnt vmcnt(0)" ::: "memory");
  }
  __builtin_amdgcn_s_barrier();

  for (int t = 0; t < NT; ++t) {
    const int b = t & 1;
    bf16x8 aF[8], bL[4], bH[4];

    // ---- phase 0: read A-lo frags + B-lo frags; MFMA Mlo x Nlo
    #pragma unroll
    for (int mi = 0; mi < 4; ++mi) { aF[mi*2] = RDA(b, mi, 0); aF[mi*2+1] = RDA(b, mi, 1); }
    #pragma unroll
    for (int ni = 0; ni < 2; ++ni) { bL[ni*2] = RDB(b, ni, 0); bL[ni*2+1] = RDB(b, ni, 1); }
    __builtin_amdgcn_s_barrier();
    asm volatile("s_waitcnt lgkmcnt(0)");
    __builtin_amdgcn_s_setprio(1);
    #pragma unroll
    for (int mi = 0; mi < 4; ++mi)
      #pragma unroll
      for (int ni = 0; ni < 2; ++ni)
        #pragma unroll
        for (int ks = 0; ks < 2; ++ks)
          acc[mi][ni] = MFMA(aF[mi*2+ks], bL[ni*2+ks], acc[mi][ni]);
    __builtin_amdgcn_s_setprio(0);
    __builtin_amdgcn_s_barrier();

    // ---- phase 1: read B-hi frags; MFMA Mlo x Nhi.  (B halves die at this
    //      phase's end barrier.)
    #pragma unroll
    for (int ni = 0; ni < 2; ++ni) { bH[ni*2] = RDB(b, ni + 2, 0); bH[ni*2+1] = RDB(b, ni + 2, 1); }
    __builtin_amdgcn_s_barrier();
    asm volatile("s_waitcnt lgkmcnt(0)");
    __builtin_amdgcn_s_setprio(1);
    #pragma unroll
    for (int mi = 0; mi < 4; ++mi)
      #pragma unroll
      for (int ni = 0; ni < 2; ++ni)
        #pragma unroll
        for (int ks = 0; ks < 2; ++ks)
          acc[mi][ni + 2] = MFMA(aF[mi*2+ks], bH[ni*2+ks], acc[mi][ni + 2]);
    __builtin_amdgcn_s_setprio(0);
    __builtin_amdgcn_s_barrier();

    // ---- phase 2: read A-hi frags; stage B(t+2) (B dead); MFMA Mhi x Nhi
    #pragma unroll
    for (int mi = 0; mi < 4; ++mi) { aF[mi*2] = RDA(b, mi + 4, 0); aF[mi*2+1] = RDA(b, mi + 4, 1); }
    if (t + 2 < NT) { STG(t + 2, 2); STG(t + 2, 3); }
    __builtin_amdgcn_s_barrier();
    asm volatile("s_waitcnt lgkmcnt(0)");
    __builtin_amdgcn_s_setprio(1);
    #pragma unroll
    for (int mi = 0; mi < 4; ++mi)
      #pragma unroll
      for (int ni = 0; ni < 2; ++ni)
        #pragma unroll
        for (int ks = 0; ks < 2; ++ks)
          acc[mi + 4][ni + 2] = MFMA(aF[mi*2+ks], bH[ni*2+ks], acc[mi + 4][ni + 2]);
    __builtin_amdgcn_s_setprio(0);
    __builtin_amdgcn_s_barrier();

    // ---- phase 3: no reads (bL live in regs); stage A(t+2) (A dead); MFMA Mhi x Nlo
    if (t + 2 < NT) { STG(t + 2, 0); STG(t + 2, 1); }
    __builtin_amdgcn_s_barrier();
    asm volatile("s_waitcnt lgkmcnt(0)");
    __builtin_amdgcn_s_setprio(1);
    #pragma unroll
    for (int mi = 0; mi < 4; ++mi)
      #pragma unroll
      for (int ni = 0; ni < 2; ++ni)
        #pragma unroll
        for (int ks = 0; ks < 2; ++ks)
          acc[mi + 4][ni] = MFMA(aF[mi*2+ks], bL[ni*2+ks], acc[mi + 4][ni]);
    __builtin_amdgcn_s_setprio(0);
    // boundary: keep this tile's 8 staging instrs in flight, drain older
    if (t < NT - 2) asm volatile("s_waitcnt vmcnt(8)" ::: "memory");
    else            asm volatile("s_waitcnt vmcnt(0)" ::: "memory");
    __builtin_amdgcn_s_barrier();
  }

  float scl = scale_ptr ? scale_ptr[0] : 1.0f;
  // C/D: col = lane&15 (=fr), row = fs*4 + reg
  #pragma unroll
  for (int mi = 0; mi < 8; ++mi) {
    #pragma unroll
    for (int ni = 0; ni < 4; ++ni) {
      #pragma unroll
      for (int r = 0; r < 4; ++r) {
        int gr = row0 + wr * 128 + mi * 16 + fs * 4 + r;
        int gc = col0 + wc * 64 + ni * 16 + fr;
        float v = acc[mi][ni][r] * scl;
        if (OUT_BF16) ((u16*)Cv)[(size_t)gr * Nn + gc] = f2bf(v);
        else          ((float*)Cv)[(size_t)gr * Nn + gc] = v;
      }
    }
  }
}

extern "C" void kernel_launch(void* const* d_in, const int* in_sizes, int n_in,
                              void* d_out, int out_size, void* d_ws, size_t ws_size,
                              hipStream_t stream) {
  const float* x    = (const float*)d_in[0];  // [N,D]
  const float* lorA = (const float*)d_in[1];  // [D,D] (rank, in)
  const float* lorB = (const float*)d_in[2];  // [D,D] (out, rank)
  const float* mag  = (const float*)d_in[3];  // [D]
  const float* dir  = (const float*)d_in[4];  // [D,D] (out, rank)
  float* out = (float*)d_out;

  char* ws = (char*)d_ws;
  u16*   xb  = (u16*)(ws);                        // 33,554,432: x in bf16
  u16*   Ab  = (u16*)(ws + 33554432);             //  8,388,608: lora_A bf16
  u16*   Bb  = (u16*)(ws + 41943040);             //  8,388,608: lora_B bf16
  u16*   Db  = (u16*)(ws + 50331648);             //  8,388,608: dirn bf16 (reused for WfT)
  u16*   CT  = (u16*)(ws + 58720256);             //  8,388,608: C^T bf16
  float* scl = (float*)(ws + 67108864);           //  4: mag*scaling
  u16*   WfT = Db;  // dirn dead after GEMM1; alias

  cvt_f32_bf16<<<2048, 256, 0, stream>>>(x,    xb, N_TOK * D_DIM / 4);
  cvt_f32_bf16<<<1024, 256, 0, stream>>>(lorA, Ab, D_DIM * D_DIM / 4);
  cvt_f32_bf16<<<1024, 256, 0, stream>>>(lorB, Bb, D_DIM * D_DIM / 4);
  normalize_rows<<<D_DIM, 256, 0, stream>>>(dir, Db);
  mag_scale_k<<<1, 256, 0, stream>>>(mag, scl, D_DIM, 16.0f / 2048.0f);

  // GEMM1: CT[o,r] = sum_i dirn[o,i] * A[r,i]
  gemm_nt<1><<<dim3(D_DIM / 128, D_DIM / 128), 256, 0, stream>>>(
      Db, Ab, CT, D_DIM, D_DIM, D_DIM, nullptr);
  // GEMM2: WfT[o,p] = sum_r CT[o,r] * B[p,r]
  gemm_nt<1><<<dim3(D_DIM / 128, D_DIM / 128), 256, 0, stream>>>(
      CT, Bb, WfT, D_DIM, D_DIM, D_DIM, nullptr);
  // GEMM3 (8-phase 256^2): out[n,o] = scale * sum_p x[n,p] * WfT[o,p]
  gemm_nt8<0><<<dim3(D_DIM / 256, N_TOK / 256), 512, 0, stream>>>(
      xb, WfT, out, N_TOK, D_DIM, D_DIM, scl);
}

// Round 9
// 311.593 us; speedup vs baseline: 1.0664x; 1.0043x over previous
//
#include <hip/hip_runtime.h>

typedef unsigned short u16;
typedef unsigned int   u32;
typedef __attribute__((ext_vector_type(8))) __bf16 bf16x8;
typedef __attribute__((ext_vector_type(4))) float  f32x4;

#define D_DIM 2048
#define N_TOK 8192

// f32 -> bf16 round-to-nearest-even
__device__ __forceinline__ u16 f2bf(float f) {
  u32 u = __float_as_uint(f);
  u32 r = (u + 0x7fffu + ((u >> 16) & 1u)) >> 16;
  return (u16)r;
}
__device__ __forceinline__ float b2f(u16 h) {
  return __uint_as_float(((u32)h) << 16);
}

__device__ __forceinline__ void gl16(const void* g, void* l) {
  __builtin_amdgcn_global_load_lds((const __attribute__((address_space(1))) void*)g,
                                   (__attribute__((address_space(3))) void*)l,
                                   16, 0, 0);
}

// ---------- elementwise f32 -> bf16 ----------
__global__ __launch_bounds__(256) void cvt_f32_bf16(const float* __restrict__ in,
                                                    u16* __restrict__ out, int n4) {
  int idx = blockIdx.x * 256 + threadIdx.x;
  int stride = gridDim.x * 256;
  for (int i = idx; i < n4; i += stride) {
    float4 v = ((const float4*)in)[i];
    ushort4 o;
    o.x = f2bf(v.x); o.y = f2bf(v.y); o.z = f2bf(v.z); o.w = f2bf(v.w);
    ((ushort4*)out)[i] = o;
  }
}

// ---------- two-array f32 -> bf16 in one launch (A in lower half, B upper) ----------
__global__ __launch_bounds__(256) void cvt2_f32_bf16(const float* __restrict__ inA,
                                                     u16* __restrict__ outA,
                                                     const float* __restrict__ inB,
                                                     u16* __restrict__ outB, int n4) {
  const int half = gridDim.x >> 1;
  const bool lo = (int)blockIdx.x < half;
  const float* in = lo ? inA : inB;
  u16* out = lo ? outA : outB;
  int bid = lo ? blockIdx.x : blockIdx.x - half;
  int idx = bid * 256 + threadIdx.x;
  int stride = half * 256;
  for (int i = idx; i < n4; i += stride) {
    float4 v = ((const float4*)in)[i];
    ushort4 o;
    o.x = f2bf(v.x); o.y = f2bf(v.y); o.z = f2bf(v.z); o.w = f2bf(v.w);
    ((ushort4*)out)[i] = o;
  }
}

// ---------- row-wise L2 normalize of direction -> bf16; block D_DIM does mag scale ----------
__global__ __launch_bounds__(256) void norm_mag(const float* __restrict__ dir,
                                                u16* __restrict__ out,
                                                const float* __restrict__ mag,
                                                float* __restrict__ scale) {
  __shared__ float red[4];
  __shared__ float invs;
  const int tid = threadIdx.x;

  if (blockIdx.x == D_DIM) {  // ||magnitude|| * alpha/D
    float ss = 0.0f;
    for (int i = tid; i < D_DIM / 4; i += 256) {
      float4 v = ((const float4*)mag)[i];
      ss += v.x*v.x + v.y*v.y + v.z*v.z + v.w*v.w;
    }
    #pragma unroll
    for (int off = 32; off > 0; off >>= 1) ss += __shfl_down(ss, off);
    if ((tid & 63) == 0) red[tid >> 6] = ss;
    __syncthreads();
    if (tid == 0) {
      float t = red[0] + red[1] + red[2] + red[3];
      scale[0] = sqrtf(t) * (16.0f / 2048.0f);
    }
    return;
  }

  const int row = blockIdx.x;
  const float4* r = (const float4*)(dir + (size_t)row * D_DIM);
  float4 v0 = r[tid * 2 + 0];
  float4 v1 = r[tid * 2 + 1];
  float ss = v0.x*v0.x + v0.y*v0.y + v0.z*v0.z + v0.w*v0.w
           + v1.x*v1.x + v1.y*v1.y + v1.z*v1.z + v1.w*v1.w;
  #pragma unroll
  for (int off = 32; off > 0; off >>= 1) ss += __shfl_down(ss, off);
  if ((tid & 63) == 0) red[tid >> 6] = ss;
  __syncthreads();
  if (tid == 0) {
    float t = red[0] + red[1] + red[2] + red[3];
    invs = 1.0f / fmaxf(sqrtf(t), 1e-12f);
  }
  __syncthreads();
  float inv = invs;
  ushort4 o0, o1;
  o0.x = f2bf(v0.x * inv); o0.y = f2bf(v0.y * inv);
  o0.z = f2bf(v0.z * inv); o0.w = f2bf(v0.w * inv);
  o1.x = f2bf(v1.x * inv); o1.y = f2bf(v1.y * inv);
  o1.z = f2bf(v1.z * inv); o1.w = f2bf(v1.w * inv);
  ushort4* ow = (ushort4*)(out + (size_t)row * D_DIM);
  ow[tid * 2 + 0] = o0;
  ow[tid * 2 + 1] = o1;
}

// ---------- NT bf16 GEMM, 128x128 tile, SPLIT-K: blockIdx.z covers K-slice ----------
// Body identical to the R2/R4-verified gemm_nt except: K-range [z*klen, z*klen+klen)
// and bf16 partial output into P + z*M*Nn. grid (Nn/128, M/128, K/klen).
__global__ __launch_bounds__(256)
void gemm_nt_sk(const u16* __restrict__ A, const u16* __restrict__ B,
                u16* __restrict__ P, int M, int Nn, int K, int klen) {
  __shared__ __align__(16) u16 lA[128 * 64];
  __shared__ __align__(16) u16 lB[128 * 64];
  const int tid  = threadIdx.x;
  const int lane = tid & 63;
  const int wave = tid >> 6;
  const int wr = wave >> 1, wc = wave & 1;
  const int row0 = blockIdx.y * 128, col0 = blockIdx.x * 128;
  const int kbeg = blockIdx.z * klen;

  const u16* Ag = A + (size_t)row0 * K;
  const u16* Bg = B + (size_t)col0 * K;

  f32x4 acc[4][4];
  #pragma unroll
  for (int i = 0; i < 4; ++i)
    #pragma unroll
    for (int j = 0; j < 4; ++j)
      acc[i][j] = (f32x4){0.0f, 0.0f, 0.0f, 0.0f};

  const int rsub = lane >> 3;
  const int sm   = lane & 7;

  for (int k0 = kbeg; k0 < kbeg + klen; k0 += 64) {
    #pragma unroll
    for (int j = 0; j < 4; ++j) {
      int c  = wave * 4 + j;
      int rt = c * 8 + rsub;
      int ssrc = sm ^ (rt & 7);
      gl16(Ag + (size_t)rt * K + k0 + ssrc * 8, &lA[c * 512 + lane * 8]);
      gl16(Bg + (size_t)rt * K + k0 + ssrc * 8, &lB[c * 512 + lane * 8]);
    }
    __syncthreads();

    #pragma unroll
    for (int ks = 0; ks < 2; ++ks) {
      bf16x8 af[4], bfr[4];
      #pragma unroll
      for (int mi = 0; mi < 4; ++mi) {
        int ra = wr * 64 + mi * 16 + (lane & 15);
        int sa = (ks * 4 + (lane >> 4)) ^ (ra & 7);
        af[mi] = *(const bf16x8*)&lA[ra * 64 + sa * 8];
        int rb = wc * 64 + mi * 16 + (lane & 15);
        int sb = (ks * 4 + (lane >> 4)) ^ (rb & 7);
        bfr[mi] = *(const bf16x8*)&lB[rb * 64 + sb * 8];
      }
      #pragma unroll
      for (int mi = 0; mi < 4; ++mi)
        #pragma unroll
        for (int ni = 0; ni < 4; ++ni)
          acc[mi][ni] = __builtin_amdgcn_mfma_f32_16x16x32_bf16(
              af[mi], bfr[ni], acc[mi][ni], 0, 0, 0);
    }
    __syncthreads();
  }

  u16* Pz = P + (size_t)blockIdx.z * M * Nn;
  const int orow = row0 + wr * 64 + (lane >> 4) * 4;
  const int ocol = col0 + wc * 64 + (lane & 15);
  #pragma unroll
  for (int mi = 0; mi < 4; ++mi)
    #pragma unroll
    for (int ni = 0; ni < 4; ++ni)
      #pragma unroll
      for (int r = 0; r < 4; ++r)
        Pz[(size_t)(orow + mi * 16 + r) * Nn + (ocol + ni * 16)] = f2bf(acc[mi][ni][r]);
}

// ---------- sum 4 bf16 partial slices -> bf16 ----------
__global__ __launch_bounds__(256) void reduce4_bf16(const u16* __restrict__ P,
                                                    u16* __restrict__ out,
                                                    int n4, int slice4) {
  int idx = blockIdx.x * 256 + threadIdx.x;
  int stride = gridDim.x * 256;
  for (int i = idx; i < n4; i += stride) {
    ushort4 a = ((const ushort4*)P)[i];
    ushort4 b = ((const ushort4*)P)[i + slice4];
    ushort4 c = ((const ushort4*)P)[i + 2 * slice4];
    ushort4 d = ((const ushort4*)P)[i + 3 * slice4];
    ushort4 o;
    o.x = f2bf(b2f(a.x) + b2f(b.x) + b2f(c.x) + b2f(d.x));
    o.y = f2bf(b2f(a.y) + b2f(b.y) + b2f(c.y) + b2f(d.y));
    o.z = f2bf(b2f(a.z) + b2f(b.z) + b2f(c.z) + b2f(d.z));
    o.w = f2bf(b2f(a.w) + b2f(b.w) + b2f(c.w) + b2f(d.w));
    ((ushort4*)out)[i] = o;
  }
}

// ---------- NT bf16 GEMM, 256x256 tile, 8-phase counted-vmcnt (R4-verified) ----------
// + bijective XCD swizzle (m204): XCD k gets a contiguous wgid chunk -> shares
// 4 x-panels + the WfT panel set in its L2.
#define STG(tile, half) do {                                                   \
    const u16* G_ = ((half) < 2) ? (A + (size_t)(row0 + ((half)&1)*128) * K)   \
                                 : (B + (size_t)(col0 + ((half)&1)*128) * K);  \
    u16* L_ = &lds[(tile)&1][half][0];                                         \
    const int k0_ = (tile) << 6;                                               \
    { int idx = tid;       int rt = idx >> 3, sm2 = idx & 7;                   \
      gl16(G_ + (size_t)rt*K + k0_ + (sm2 ^ (rt&7))*8, L_ + idx*8); }          \
    { int idx = 512 + tid; int rt = idx >> 3, sm2 = idx & 7;                   \
      gl16(G_ + (size_t)rt*K + k0_ + (sm2 ^ (rt&7))*8, L_ + idx*8); }          \
  } while (0)

#define RDA(b, mi, ks) (*(const bf16x8*)&lds[b][wr][((mi)*16 + fr)*64 + ((((ks)*4 + fs) ^ (fr & 7)))*8])
#define RDB(b, ni, ks) (*(const bf16x8*)&lds[b][2 + ((wc*64 + (ni)*16 + fr) >> 7)][((wc*64 + (ni)*16 + fr) & 127)*64 + ((((ks)*4 + fs) ^ (fr & 7)))*8])
#define MFMA(a, bb, c) __builtin_amdgcn_mfma_f32_16x16x32_bf16(a, bb, c, 0, 0, 0)

template <int OUT_BF16>
__global__ __launch_bounds__(512, 2)
void gemm_nt8(const u16* __restrict__ A, const u16* __restrict__ B,
              void* __restrict__ Cv, int M, int Nn, int K,
              const float* __restrict__ scale_ptr) {
  __shared__ __align__(16) u16 lds[2][4][128 * 64];  // 128 KiB
  const int tid  = threadIdx.x;
  const int lane = tid & 63;
  const int wave = tid >> 6;
  const int wr = wave >> 2;
  const int wc = wave & 3;

  // bijective XCD swizzle (m204); wgid = chunk(xcd) + lid/8
  const int nwg = gridDim.x * gridDim.y;
  const int lid = blockIdx.y * gridDim.x + blockIdx.x;
  const int q = nwg >> 3, r = nwg & 7;
  const int xcd = lid & 7, i8 = lid >> 3;
  const int wg = (xcd < r ? xcd * (q + 1) : r * (q + 1) + (xcd - r) * q) + i8;
  const int by = wg / gridDim.x, bx = wg - by * gridDim.x;

  const int row0 = by * 256, col0 = bx * 256;
  const int NT = K >> 6;
  const int fr = lane & 15, fs = lane >> 4;

  f32x4 acc[8][4];
  #pragma unroll
  for (int i = 0; i < 8; ++i)
    #pragma unroll
    for (int j = 0; j < 4; ++j)
      acc[i][j] = (f32x4){0.0f, 0.0f, 0.0f, 0.0f};

  // prologue: stage tiles 0 and 1 fully; land tile 0, keep tile 1 in flight
  STG(0, 0); STG(0, 1); STG(0, 2); STG(0, 3);
  if (NT > 1) {
    STG(1, 0); STG(1, 1); STG(1, 2); STG(1, 3);
    asm volatile("s_waitcnt vmcnt(8)" ::: "memory");
  } else {
    asm volatile("s_waitcnt vmcnt(0)" ::: "memory");
  }
  __builtin_amdgcn_s_barrier();

  for (int t = 0; t < NT; ++t) {
    const int b = t & 1;
    bf16x8 aF[8], bL[4], bH[4];

    // ---- phase 0: read A-lo + B-lo frags; MFMA Mlo x Nlo
    #pragma unroll
    for (int mi = 0; mi < 4; ++mi) { aF[mi*2] = RDA(b, mi, 0); aF[mi*2+1] = RDA(b, mi, 1); }
    #pragma unroll
    for (int ni = 0; ni < 2; ++ni) { bL[ni*2] = RDB(b, ni, 0); bL[ni*2+1] = RDB(b, ni, 1); }
    __builtin_amdgcn_s_barrier();
    asm volatile("s_waitcnt lgkmcnt(0)");
    __builtin_amdgcn_s_setprio(1);
    #pragma unroll
    for (int mi = 0; mi < 4; ++mi)
      #pragma unroll
      for (int ni = 0; ni < 2; ++ni)
        #pragma unroll
        for (int ks = 0; ks < 2; ++ks)
          acc[mi][ni] = MFMA(aF[mi*2+ks], bL[ni*2+ks], acc[mi][ni]);
    __builtin_amdgcn_s_setprio(0);
    __builtin_amdgcn_s_barrier();

    // ---- phase 1: read B-hi frags; MFMA Mlo x Nhi (B dies at this end-barrier)
    #pragma unroll
    for (int ni = 0; ni < 2; ++ni) { bH[ni*2] = RDB(b, ni + 2, 0); bH[ni*2+1] = RDB(b, ni + 2, 1); }
    __builtin_amdgcn_s_barrier();
    asm volatile("s_waitcnt lgkmcnt(0)");
    __builtin_amdgcn_s_setprio(1);
    #pragma unroll
    for (int mi = 0; mi < 4; ++mi)
      #pragma unroll
      for (int ni = 0; ni < 2; ++ni)
        #pragma unroll
        for (int ks = 0; ks < 2; ++ks)
          acc[mi][ni + 2] = MFMA(aF[mi*2+ks], bH[ni*2+ks], acc[mi][ni + 2]);
    __builtin_amdgcn_s_setprio(0);
    __builtin_amdgcn_s_barrier();

    // ---- phase 2: read A-hi frags; stage B(t+2) (B dead); MFMA Mhi x Nhi
    #pragma unroll
    for (int mi = 0; mi < 4; ++mi) { aF[mi*2] = RDA(b, mi + 4, 0); aF[mi*2+1] = RDA(b, mi + 4, 1); }
    if (t + 2 < NT) { STG(t + 2, 2); STG(t + 2, 3); }
    __builtin_amdgcn_s_barrier();
    asm volatile("s_waitcnt lgkmcnt(0)");
    __builtin_amdgcn_s_setprio(1);
    #pragma unroll
    for (int mi = 0; mi < 4; ++mi)
      #pragma unroll
      for (int ni = 0; ni < 2; ++ni)
        #pragma unroll
        for (int ks = 0; ks < 2; ++ks)
          acc[mi + 4][ni + 2] = MFMA(aF[mi*2+ks], bH[ni*2+ks], acc[mi + 4][ni + 2]);
    __builtin_amdgcn_s_setprio(0);
    __builtin_amdgcn_s_barrier();

    // ---- phase 3: no reads (bL live in regs); stage A(t+2) (A dead); MFMA Mhi x Nlo
    if (t + 2 < NT) { STG(t + 2, 0); STG(t + 2, 1); }
    __builtin_amdgcn_s_barrier();
    asm volatile("s_waitcnt lgkmcnt(0)");
    __builtin_amdgcn_s_setprio(1);
    #pragma unroll
    for (int mi = 0; mi < 4; ++mi)
      #pragma unroll
      for (int ni = 0; ni < 2; ++ni)
        #pragma unroll
        for (int ks = 0; ks < 2; ++ks)
          acc[mi + 4][ni] = MFMA(aF[mi*2+ks], bL[ni*2+ks], acc[mi + 4][ni]);
    __builtin_amdgcn_s_setprio(0);
    if (t < NT - 2) asm volatile("s_waitcnt vmcnt(8)" ::: "memory");
    else            asm volatile("s_waitcnt vmcnt(0)" ::: "memory");
    __builtin_amdgcn_s_barrier();
  }

  float scl = scale_ptr ? scale_ptr[0] : 1.0f;
  #pragma unroll
  for (int mi = 0; mi < 8; ++mi) {
    #pragma unroll
    for (int ni = 0; ni < 4; ++ni) {
      #pragma unroll
      for (int r = 0; r < 4; ++r) {
        int gr = row0 + wr * 128 + mi * 16 + fs * 4 + r;
        int gc = col0 + wc * 64 + ni * 16 + fr;
        float v = acc[mi][ni][r] * scl;
        if (OUT_BF16) ((u16*)Cv)[(size_t)gr * Nn + gc] = f2bf(v);
        else          ((float*)Cv)[(size_t)gr * Nn + gc] = v;
      }
    }
  }
}

extern "C" void kernel_launch(void* const* d_in, const int* in_sizes, int n_in,
                              void* d_out, int out_size, void* d_ws, size_t ws_size,
                              hipStream_t stream) {
  const float* x    = (const float*)d_in[0];  // [N,D]
  const float* lorA = (const float*)d_in[1];  // [D,D] (rank, in)
  const float* lorB = (const float*)d_in[2];  // [D,D] (out, rank)
  const float* mag  = (const float*)d_in[3];  // [D]
  const float* dir  = (const float*)d_in[4];  // [D,D] (out, rank)
  float* out = (float*)d_out;

  char* ws = (char*)d_ws;
  // xb region (33.5 MB) double-duty: split-K partials (4 x 8.4 MB bf16) during
  // GEMM1/2, then x-bf16 (converted AFTER reduce2 consumed the partials).
  u16*   xb  = (u16*)(ws);                        // 33,554,432
  u16*   Pp  = xb;                                // alias: split-K partials
  u16*   Ab  = (u16*)(ws + 33554432);             //  8,388,608: lora_A bf16
  u16*   Bb  = (u16*)(ws + 41943040);             //  8,388,608: lora_B bf16
  u16*   Db  = (u16*)(ws + 50331648);             //  8,388,608: dirn bf16 -> WfT
  u16*   CT  = (u16*)(ws + 58720256);             //  8,388,608: C^T bf16
  float* scl = (float*)(ws + 67108864);           //  4: ||mag||*scaling
  u16*   WfT = Db;

  // prep (x conversion deferred until after reduce2 — xb holds partials first)
  cvt2_f32_bf16<<<2048, 256, 0, stream>>>(lorA, Ab, lorB, Bb, D_DIM * D_DIM / 4);
  norm_mag<<<D_DIM + 1, 256, 0, stream>>>(dir, Db, mag, scl);

  // GEMM1 (split-K=4): CT[o,r] = sum_i dirn[o,i] * A[r,i]
  gemm_nt_sk<<<dim3(16, 16, 4), 256, 0, stream>>>(Db, Ab, Pp, D_DIM, D_DIM, D_DIM, 512);
  reduce4_bf16<<<1024, 256, 0, stream>>>(Pp, CT, D_DIM * D_DIM / 4, D_DIM * D_DIM / 4);

  // GEMM2 (split-K=4): WfT[o,p] = sum_r CT[o,r] * B[p,r]
  gemm_nt_sk<<<dim3(16, 16, 4), 256, 0, stream>>>(CT, Bb, Pp, D_DIM, D_DIM, D_DIM, 512);
  reduce4_bf16<<<1024, 256, 0, stream>>>(Pp, WfT, D_DIM * D_DIM / 4, D_DIM * D_DIM / 4);

  // now xb is free: convert x
  cvt_f32_bf16<<<2048, 256, 0, stream>>>(x, xb, N_TOK * D_DIM / 4);

  // GEMM3 (8-phase 256^2 + XCD swizzle): out[n,o] = scale * sum_p x[n,p] * WfT[o,p]
  gemm_nt8<0><<<dim3(D_DIM / 256, N_TOK / 256), 512, 0, stream>>>(
      xb, WfT, out, N_TOK, D_DIM, D_DIM, scl);
}